// Round 6
// baseline (212.527 us; speedup 1.0000x reference)
//
#include <hip/hip_runtime.h>
#include <stdint.h>

// FPGAQuantizedLinear: out = (clip(round(x/0.02),-128,127) @ W_int8) * 2e-4 + bias
// x: (32768, 768) fp32, W^T logical [K=768][M=768] int8 but DELIVERED AS INT32
// (harness materializes every integer input as const int*), bias: (768,) fp32.
//
// Memory-bound (201 MB traffic vs ~9us of i8 MFMA). Structure:
//   1. repack_kernel: weight (int32-widened) -> int8 MFMA-B-fragment order in
//      d_ws (589,824 B). Layout:
//      bpack[(mt*24+kt)*1024 + lane*16 + j] = W[kt*32+(lane>>5)*16+j][mt*32+(lane&31)]
//      so the hot loop's B load is one coalesced global_load_dwordx4 per lane.
//   2. qlinear_kernel: 512 blocks x 512 threads. BM=64 rows, all 768 cols per block
//      (x read exactly once from HBM; weight L2-resident).
//      Stage: quantize fp32->int8 into LDS [64][768] with XOR swizzle (row&7)<<4
//      (fixes the 32-way bank conflict of stride-768 ds_read_b128 A-frag reads).
//      Compute: 8 waves = 2 row-groups x 4 col-groups; per col-iter (6 total)
//      each wave does 24x mfma_i32_32x32x32_i8, then dequant+bias epilogue.
//   If ws_size is too small for bpack (container-safety guard), fall back to a
//   correct-but-slow path that gathers B fragments directly from w (L2-hot).

typedef __attribute__((ext_vector_type(4))) int i32x4;
typedef __attribute__((ext_vector_type(16))) int i32x16;

#define K_DIM 768
#define M_DIM 768
#define BM 64
#define KT_N 24  // K/32
#define MT_N 24  // M/32
#define BPACK_BYTES (MT_N * KT_N * 1024)  // 589,824

__global__ __launch_bounds__(256) void repack_kernel(const int* __restrict__ w,
                                                     int8_t* __restrict__ bp) {
  const int gid = blockIdx.x * 256 + threadIdx.x;
  const int gw = gid >> 6;  // global wave id, 0..575 = (mt,kt)
  const int lane = gid & 63;
  if (gw >= MT_N * KT_N) return;
  const int mt = gw / KT_N;
  const int kt = gw - mt * KT_N;
  const int col = (mt << 5) + (lane & 31);
  const int krow = (kt << 5) + ((lane >> 5) << 4);
  int8_t buf[16];
#pragma unroll
  for (int j = 0; j < 16; ++j)
    buf[j] = (int8_t)w[(size_t)(krow + j) * M_DIM + col];  // int32 -> int8 value
  *reinterpret_cast<i32x4*>(bp + ((size_t)gw << 10) + (lane << 4)) =
      *reinterpret_cast<const i32x4*>(buf);
}

__device__ __forceinline__ int quant1(float v) {
  // IEEE f32 divide + round-half-even (v_rndne): bit-identical to jnp round(x/0.02).
  float r = __builtin_rintf(v / 0.02f);
  r = fminf(fmaxf(r, -128.0f), 127.0f);
  return (int)r;
}

template <bool USE_BPACK>
__global__ __launch_bounds__(512, 2) void qlinear_kernel(
    const float* __restrict__ x, const int8_t* __restrict__ bpack,
    const int* __restrict__ w, const float* __restrict__ bias,
    float* __restrict__ out) {
  __shared__ int8_t alds[BM * 768];  // 48 KB, XOR-swizzled int8 A-tile
  const int t = threadIdx.x;
  const int brow = blockIdx.x * BM;

  // ---- stage: load fp32 x-tile, quantize, write int8 to LDS (swizzled) ----
  {
    const int tr = t >> 3;           // 0..63 row within tile
    const int tk = t & 7;            // 8 threads per row
    const float* __restrict__ xr = x + (size_t)(brow + tr) * K_DIM;
    int8_t* arow = alds + tr * 768;
    const int sw = (tr & 7) << 4;    // XOR swizzle for this row
#pragma unroll
    for (int i = 0; i < 24; ++i) {
      const int k4 = tk + (i << 3);  // float4 index within row (stride 8 -> coalesced)
      const float4 v = *reinterpret_cast<const float4*>(xr + (k4 << 2));
      const int q0 = quant1(v.x);
      const int q1 = quant1(v.y);
      const int q2 = quant1(v.z);
      const int q3 = quant1(v.w);
      const int packed = (q0 & 255) | ((q1 & 255) << 8) | ((q2 & 255) << 16) | (q3 << 24);
      *reinterpret_cast<int*>(arow + ((k4 << 2) ^ sw)) = packed;
    }
  }
  __syncthreads();

  // ---- compute: 8 waves = (wr 0..1) x (wc 0..3) ----
  const int lane = t & 63;
  const int wave = t >> 6;
  const int wr = wave >> 2;
  const int wc = wave & 3;
  const int arow_i = (wr << 5) + (lane & 31);     // A row this lane reads
  const int abase = arow_i * 768;
  const int asw = (arow_i & 7) << 4;              // matching read-side swizzle
  const int kofl = (lane >> 5) << 4;              // k offset for lane-half
  const float deq = (float)(0.02 * 0.01);         // EFF_SCALE as f32

#pragma unroll 1
  for (int ci = 0; ci < 6; ++ci) {
    const int mt = (ci << 2) + wc;                // 32-col tile index
    const int col = (mt << 5) + (lane & 31);
    const int8_t* __restrict__ bp = bpack + ((size_t)(mt * KT_N) << 10) + (lane << 4);
    i32x16 acc = {};
#pragma unroll
    for (int kt = 0; kt < KT_N; ++kt) {
      const i32x4 a = *reinterpret_cast<const i32x4*>(
          alds + abase + ((((kt << 5) + kofl)) ^ asw));
      i32x4 b;
      if constexpr (USE_BPACK) {
        b = *reinterpret_cast<const i32x4*>(bp + (kt << 10));
      } else {
        // slow fallback: strided int32 gather from w (L2-resident)
        int8_t tmp[16];
        const int k0 = (kt << 5) + kofl;
#pragma unroll
        for (int j = 0; j < 16; ++j)
          tmp[j] = (int8_t)w[(size_t)(k0 + j) * M_DIM + col];
        b = *reinterpret_cast<const i32x4*>(tmp);
      }
      acc = __builtin_amdgcn_mfma_i32_32x32x32_i8(a, b, acc, 0, 0, 0);
    }
    // ---- epilogue: C layout col=lane&31, row=(reg&3)+8*(reg>>2)+4*(lane>>5) ----
    const float bv = bias[col];
    float* __restrict__ op =
        out + (size_t)(brow + (wr << 5) + ((lane >> 5) << 2)) * M_DIM + col;
#pragma unroll
    for (int r = 0; r < 16; ++r) {
      const int rr = (r & 3) + ((r >> 2) << 3);
      op[(size_t)rr * M_DIM] = (float)acc[r] * deq + bv;
    }
  }
}

extern "C" void kernel_launch(void* const* d_in, const int* in_sizes, int n_in,
                              void* d_out, int out_size, void* d_ws, size_t ws_size,
                              hipStream_t stream) {
  const float* x = (const float*)d_in[0];
  const int* w = (const int*)d_in[1];  // int8 values widened to int32 by harness
  const float* bias = (const float*)d_in[2];
  float* out = (float*)d_out;
  int8_t* bpack = (int8_t*)d_ws;

  const int nrows = in_sizes[0] / K_DIM;  // 32768
  const int nblk = nrows / BM;            // 512

  if (ws_size >= (size_t)BPACK_BYTES) {
    // 576 waves total, 4 per block -> 144 blocks (exact).
    repack_kernel<<<144, 256, 0, stream>>>(w, bpack);
    qlinear_kernel<true><<<nblk, 512, 0, stream>>>(x, bpack, w, bias, out);
  } else {
    qlinear_kernel<false><<<nblk, 512, 0, stream>>>(x, bpack, w, bias, out);
  }
}